// Round 8
// baseline (309.514 us; speedup 1.0000x reference)
//
#include <hip/hip_runtime.h>
#include <hip/hip_bf16.h>
#include <hip/hip_fp16.h>

#define NN 100000     // nodes
#define FIN 128
#define EMB 64
#define SCAN_B 256
#define NGRP 8                  // dst-range groups, aligned to XCDs
#define GRP_SZ (NN / NGRP)      // 12500

using half8 = __attribute__((ext_vector_type(8))) _Float16;
using f32x4 = __attribute__((ext_vector_type(4))) float;

// ---------------------------------------------------------------- degree ----
// Streaming dst read is non-temporal so it doesn't evict the cnt lines being
// atomically accumulated in this XCD's L2.
__global__ void cnt_count_k(const int* __restrict__ dst, int* __restrict__ cnt, int n_edges) {
    const int g   = blockIdx.x & (NGRP - 1);
    const int nb  = gridDim.x >> 3;
    const int bid = blockIdx.x >> 3;
    const int lo  = g * GRP_SZ, hi = lo + GRP_SZ;
    for (int base = bid * 256; base < n_edges; base += nb * 256) {
        int e = base + threadIdx.x;
        if (e < n_edges) {
            int d = __builtin_nontemporal_load(dst + e);
            if (d >= lo && d < hi) atomicAdd(&cnt[d], 1);
        }
    }
}

// ---------------------------------------------------------------- scan ------
__global__ void scan1_k(const int* __restrict__ cnt, int* __restrict__ excl,
                        int* __restrict__ bsum, float* __restrict__ dinv, int n) {
    __shared__ int tmp[SCAN_B];
    int tid = threadIdx.x;
    int i = blockIdx.x * SCAN_B + tid;
    int v = (i < n) ? cnt[i] : 0;
    if (i < n) dinv[i] = rsqrtf((float)(v + 1));   // +1 self-loop
    tmp[tid] = v; __syncthreads();
    for (int off = 1; off < SCAN_B; off <<= 1) {
        int t = (tid >= off) ? tmp[tid - off] : 0; __syncthreads();
        tmp[tid] += t; __syncthreads();
    }
    if (i < n) excl[i] = tmp[tid] - v;
    if (tid == SCAN_B - 1) bsum[blockIdx.x] = tmp[tid];
}

__global__ void scan2_k(int* __restrict__ bsum, int nb) {   // single block, nb<=512
    __shared__ int tmp[512];
    int tid = threadIdx.x;
    int v = (tid < nb) ? bsum[tid] : 0;
    tmp[tid] = v; __syncthreads();
    for (int off = 1; off < 512; off <<= 1) {
        int t = (tid >= off) ? tmp[tid - off] : 0; __syncthreads();
        tmp[tid] += t; __syncthreads();
    }
    if (tid < nb) bsum[tid] = tmp[tid] - v;
}

__global__ void scan3_k(const int* __restrict__ excl, const int* __restrict__ bsum,
                        int* __restrict__ rowptr, int* __restrict__ fill, int n, int n_edges) {
    int i = blockIdx.x * SCAN_B + threadIdx.x;
    if (i < n) {
        int r = excl[i] + bsum[blockIdx.x];
        rowptr[i] = r;
        fill[i] = r;
    }
    if (i == 0) rowptr[n] = n_edges;
}

// ---------------------------------------------------------------- fill ------
// Non-temporal streaming reads keep the group's csr slice (~800KB) resident
// in its XCD's L2 until lines are full -> single write-back per line.
__global__ void fill_k(const int* __restrict__ src, const int* __restrict__ dst,
                       int* __restrict__ fillp, int* __restrict__ csr, int n_edges) {
    const int g   = blockIdx.x & (NGRP - 1);
    const int nb  = gridDim.x >> 3;
    const int bid = blockIdx.x >> 3;
    const int lo  = g * GRP_SZ, hi = lo + GRP_SZ;
    for (int base = bid * 256; base < n_edges; base += nb * 256) {
        int e = base + threadIdx.x;
        if (e < n_edges) {
            int d = __builtin_nontemporal_load(dst + e);
            if (d >= lo && d < hi) {
                int s = __builtin_nontemporal_load(src + e);
                int pos = atomicAdd(&fillp[d], 1);
                csr[pos] = s;
            }
        }
    }
}

// ------------------------------------------------------------ MFMA GEMM ----
template <int K, typename TIN>
__global__ void gemm_mfma_k(const TIN* __restrict__ X, const float* __restrict__ W,
                            const float* __restrict__ dinv, __half* __restrict__ Y,
                            int n_tiles) {
    __shared__ _Float16 Wl[K * 64];
    for (int i = threadIdx.x; i < K * 64; i += 256) Wl[i] = (_Float16)W[i];
    __syncthreads();

    const int lane = threadIdx.x & 63;
    const int wid  = threadIdx.x >> 6;   // 0..3
    const int col0 = lane & 15;
    const int kg   = lane >> 4;          // 0..3

    half8 bf[4][K / 32];
#pragma unroll
    for (int t = 0; t < 4; ++t)
#pragma unroll
        for (int s = 0; s < K / 32; ++s) {
            half8 b;
#pragma unroll
            for (int j = 0; j < 8; ++j) {
                int k = s * 32 + kg * 8 + j;
                b[j] = Wl[k * 64 + t * 16 + col0];
            }
            bf[t][s] = b;
        }

    const int nwaves = gridDim.x * 4;
    for (int tile = blockIdx.x * 4 + wid; tile < n_tiles; tile += nwaves) {
        const int row0 = tile * 16;
        const int arow = row0 + col0;

        half8 af[K / 32];
#pragma unroll
        for (int s = 0; s < K / 32; ++s) {
            if constexpr (sizeof(TIN) == 4) {
                const float* p = (const float*)X + (size_t)arow * K + s * 32 + kg * 8;
                f32x4 v0 = *(const f32x4*)p;
                f32x4 v1 = *(const f32x4*)(p + 4);
                half8 a;
#pragma unroll
                for (int j = 0; j < 4; ++j) { a[j] = (_Float16)v0[j]; a[4 + j] = (_Float16)v1[j]; }
                af[s] = a;
            } else {
                const __half* p = (const __half*)X + (size_t)arow * K + s * 32 + kg * 8;
                af[s] = *(const half8*)p;
            }
        }

        f32x4 acc[4];
#pragma unroll
        for (int t = 0; t < 4; ++t) acc[t] = (f32x4){0.f, 0.f, 0.f, 0.f};
#pragma unroll
        for (int s = 0; s < K / 32; ++s)
#pragma unroll
            for (int t = 0; t < 4; ++t)
                acc[t] = __builtin_amdgcn_mfma_f32_16x16x32_f16(af[s], bf[t][s], acc[t], 0, 0, 0);

        float dv[4];
#pragma unroll
        for (int r = 0; r < 4; ++r) dv[r] = dinv[row0 + kg * 4 + r];
#pragma unroll
        for (int t = 0; t < 4; ++t)
#pragma unroll
            for (int r = 0; r < 4; ++r) {
                int row = row0 + kg * 4 + r;
                Y[(size_t)row * 64 + t * 16 + col0] = __float2half(acc[t][r] * dv[r]);
            }
    }
}

// --------------------------------------------------------------- gather -----
__global__ void gather_k(const float2* __restrict__ H4, const float* __restrict__ dinv,
                         const int* __restrict__ rowptr, const int* __restrict__ csr,
                         const float* __restrict__ bias, uint2* __restrict__ out4) {
    int node = (blockIdx.x * blockDim.x + threadIdx.x) >> 6;
    if (node >= NN) return;
    const int lane = threadIdx.x & 63;
    const int q  = lane >> 4;      // quarter 0..3 (row group)
    const int fl = lane & 15;      // feature 4-pack (features 4fl..4fl+3)

    const int p0 = rowptr[node], p1 = rowptr[node + 1];

    float4 acc = make_float4(0.f, 0.f, 0.f, 0.f);
    if (q == 0) {                  // self-loop row
        float2 v = H4[(size_t)node * 16 + fl];
        const __half2* h = (const __half2*)&v;
        float2 a = __half22float2(h[0]), b = __half22float2(h[1]);
        acc.x += a.x; acc.y += a.y; acc.z += b.x; acc.w += b.y;
    }

    for (int base = p0; base < p1; base += 64) {
        int pos = base + lane;
        int cidx = (pos < p1) ? csr[pos] : 0;       // one coalesced read / chunk
        int m = p1 - base; if (m > 64) m = 64;
        int jmax = (m + 3) >> 2;                    // wave-uniform trip count
#pragma unroll 4
        for (int j = 0; j < jmax; ++j) {
            int nb = (j << 2) + q;                  // this quarter's neighbor slot
            int s = __shfl(cidx, nb, 64);           // all 64 lanes execute
            if (nb < m) {
                float2 v = H4[(size_t)s * 16 + fl];
                const __half2* h = (const __half2*)&v;
                float2 a = __half22float2(h[0]), b = __half22float2(h[1]);
                acc.x += a.x; acc.y += a.y; acc.z += b.x; acc.w += b.y;
            }
        }
    }

    // combine the 4 quarters
    acc.x += __shfl_xor(acc.x, 16, 64); acc.y += __shfl_xor(acc.y, 16, 64);
    acc.z += __shfl_xor(acc.z, 16, 64); acc.w += __shfl_xor(acc.w, 16, 64);
    acc.x += __shfl_xor(acc.x, 32, 64); acc.y += __shfl_xor(acc.y, 32, 64);
    acc.z += __shfl_xor(acc.z, 32, 64); acc.w += __shfl_xor(acc.w, 32, 64);

    if (q == 0) {
        float di = dinv[node];
        float4 b = ((const float4*)bias)[fl];
        float vx = fmaxf(fmaf(acc.x, di, b.x), 0.f);
        float vy = fmaxf(fmaf(acc.y, di, b.y), 0.f);
        float vz = fmaxf(fmaf(acc.z, di, b.z), 0.f);
        float vw = fmaxf(fmaf(acc.w, di, b.w), 0.f);
        __half2 lo = __floats2half2_rn(vx, vy), hi = __floats2half2_rn(vz, vw);
        uint2 o; o.x = *(const uint*)&lo; o.y = *(const uint*)&hi;
        out4[(size_t)node * 16 + fl] = o;
    }
}

// ------------------------------------------------------------- head ---------
__global__ void head_k(const __half2* __restrict__ H2, const float* __restrict__ W3,
                       const float* __restrict__ b3, float* __restrict__ out) {
    int wave = (blockIdx.x * blockDim.x + threadIdx.x) >> 6;
    const int lane = threadIdx.x & 63;
    const int half = lane >> 5;
    const int fl   = lane & 31;
    int node = wave * 2 + half;
    if (node >= NN) return;
    float2 h = __half22float2(H2[(size_t)node * 32 + fl]);
    float2 w = ((const float2*)W3)[fl];
    float v = h.x * w.x + h.y * w.y;
#pragma unroll
    for (int off = 16; off > 0; off >>= 1) v += __shfl_xor(v, off, 64);
    if (fl == 0) out[node] = v + b3[0];
}

// ---------------------------------------------------------------------------
extern "C" void kernel_launch(void* const* d_in, const int* in_sizes, int n_in,
                              void* d_out, int out_size, void* d_ws, size_t ws_size,
                              hipStream_t stream) {
    const float* x   = (const float*)d_in[0];
    const int*   ei  = (const int*)d_in[1];
    const float* W1  = (const float*)d_in[2];
    const float* b1  = (const float*)d_in[3];
    const float* W2  = (const float*)d_in[4];
    const float* b2  = (const float*)d_in[5];
    const float* W3  = (const float*)d_in[6];
    const float* b3  = (const float*)d_in[7];
    float* out = (float*)d_out;

    const int E = in_sizes[1] / 2;
    const int* src = ei;
    const int* dst = ei + E;

    // workspace layout (4B units):
    // dinv[N] | cnt[N] | excl[N] | rowptr[N+1] | fill[N] | bsum[512] | csr[E]
    // | bufA (N*64 fp16) | bufB (same)
    float* dinv  = (float*)d_ws;
    int* cnt     = (int*)(dinv + NN);
    int* excl    = cnt + NN;
    int* rowptr  = excl + NN;
    int* fillp   = rowptr + NN + 1;
    int* bsum    = fillp + NN;
    int* csr     = bsum + 512;
    __half* bufA = (__half*)(csr + E);
    __half* bufB = bufA + (size_t)NN * EMB;

    const int B = 256;
    const int gNw = (NN * 64 + B - 1) / B;     // one wave per node
    const int gNh = (NN + 7) / 8;              // head: 8 nodes per block
    const int nb  = (NN + SCAN_B - 1) / SCAN_B;
    const int gFill = 1024;                    // 128 blocks per XCD group
    const int nTiles = NN / 16;                // 6250 exact
    const int gGemm = (nTiles + 3) / 4;        // 4 waves per block

    // ---- CSR build ----
    hipMemsetAsync(cnt, 0, NN * sizeof(int), stream);
    cnt_count_k<<<gFill, B, 0, stream>>>(dst, cnt, E);
    scan1_k<<<nb, SCAN_B, 0, stream>>>(cnt, excl, bsum, dinv, NN);
    scan2_k<<<1, 512, 0, stream>>>(bsum, nb);
    scan3_k<<<nb, SCAN_B, 0, stream>>>(excl, bsum, rowptr, fillp, NN, E);
    fill_k<<<gFill, B, 0, stream>>>(src, dst, fillp, csr, E);

    // ---- layer 1 ----
    gemm_mfma_k<FIN, float><<<gGemm, B, 0, stream>>>(x, W1, dinv, bufA, nTiles);
    gather_k<<<gNw, B, 0, stream>>>((const float2*)bufA, dinv, rowptr, csr, b1,
                                    (uint2*)bufB);

    // ---- layer 2 ----
    gemm_mfma_k<EMB, __half><<<gGemm, B, 0, stream>>>(bufB, W2, dinv, bufA, nTiles);
    gather_k<<<gNw, B, 0, stream>>>((const float2*)bufA, dinv, rowptr, csr, b2,
                                    (uint2*)bufB);

    // ---- head ----
    head_k<<<gNh, B, 0, stream>>>((const __half2*)bufB, W3, b3, out);
}